// Round 3
// baseline (170.536 us; speedup 1.0000x reference)
//
#include <hip/hip_runtime.h>
#include <hip/hip_bf16.h>

// Problem: T=2048, B=32, H=512
//   scores[b,t] = sum_o v[o] * tanh( hb[b,o] + sum_h enc[t,b,h] * W2[o,h] )
//   out[b,0,t]  = softmax_t(scores[b,:])
// where hb[b,o] = sum_h hidden[b,h]*W_attn[o,h] + b_attn[o],  W2[o,h] = W_attn[o, 512+h]

#define TT 2048
#define BB 32
#define HH 512

typedef __attribute__((ext_vector_type(8))) short bf16x8;
typedef __attribute__((ext_vector_type(4))) float f32x4;

static __device__ __forceinline__ unsigned cvt2(float a, float b) {
    union { __hip_bfloat162 h; unsigned u; } cv;
    cv.h = __float22bfloat162_rn(make_float2(a, b));   // v_cvt_pk_bf16_f32
    return cv.u;
}

// tanh(x) = 1 - 2/(1+e^{2x});  e=inf -> rcp(inf)=0 -> 1;  e->0 -> -1. Inf-safe.
static __device__ __forceinline__ float fast_tanh(float x) {
    float e = __expf(2.0f * x);
    return 1.0f - 2.0f * __builtin_amdgcn_rcpf(1.0f + e);
}

// ---- Kernel 1: pack W2 (= W_attn[:, 512:1024]) into fragment-major bf16.
// slot s = (ob*16 + ks)*64 + lane ; lane holds W2[o = ob*16 + (lane&15)][k = ks*32 + (lane>>4)*8 .. +7]
// so a wave's B-fragment load for (ob, ks) is one contiguous 1KB read.
__global__ void pack_w2_kernel(const float* __restrict__ W, short* __restrict__ W2p) {
    int s = blockIdx.x * 256 + threadIdx.x;        // 32768 slots
    int lane = s & 63;
    int ks = (s >> 6) & 15;
    int ob = s >> 10;
    int o = ob * 16 + (lane & 15);
    int k = ks * 32 + (lane >> 4) * 8;
    const float* src = W + (size_t)o * 1024 + 512 + k;
    uint4 pk;
    pk.x = cvt2(src[0], src[1]);
    pk.y = cvt2(src[2], src[3]);
    pk.z = cvt2(src[4], src[5]);
    pk.w = cvt2(src[6], src[7]);
    *reinterpret_cast<uint4*>(W2p + (size_t)s * 8) = pk;
}

// ---- Kernel 2: hb[b][o] = b_attn[o] + sum_h hidden[b,h] * W_attn[o,h]
__global__ void hb_kernel(const float* __restrict__ hidden, const float* __restrict__ W,
                          const float* __restrict__ b_attn, float* __restrict__ hb) {
    __shared__ float hrow[512];
    int b = blockIdx.x >> 1;
    int o = ((blockIdx.x & 1) << 8) + threadIdx.x;
    for (int h = threadIdx.x; h < 512; h += 256) hrow[h] = hidden[b * 512 + h];
    __syncthreads();
    const float4* wr = reinterpret_cast<const float4*>(W + (size_t)o * 1024);
    const float4* hr = reinterpret_cast<const float4*>(hrow);
    float acc = b_attn[o];
#pragma unroll 8
    for (int i = 0; i < 128; ++i) {
        float4 w = wr[i], h4 = hr[i];
        acc += w.x * h4.x + w.y * h4.y + w.z * h4.z + w.w * h4.w;
    }
    hb[b * 512 + o] = acc;
}

// ---- Kernel 3: fused GEMM + tanh + v-dot -> scores[b][t]
// Block: 256 threads (4 waves). Tile: 32 t-rows for one b, full K=512 in LDS (bf16, swizzled).
// 2048 blocks (32 b x 64 t-tiles); ~33KB LDS -> 4 blocks/CU -> 16 waves/CU.
// o processed in 4 chunks of 128 (wave w owns cols [chunk*128 + w*32, +32)).
__global__ __launch_bounds__(256, 4) void attn_main_kernel(
    const float* __restrict__ enc, const short* __restrict__ W2p,
    const float* __restrict__ hb, const float* __restrict__ v,
    float* __restrict__ scores)
{
    __shared__ short At[32 * 512];   // 32KB, swizzled: idx = (m*512+c) ^ ((m&7)<<3)
    __shared__ float s_red[4][32];

    const int tid = threadIdx.x;
    const int b = blockIdx.x >> 6;          // 32 b's
    const int t0 = (blockIdx.x & 63) * 32;  // 64 t-tiles

    // ---- stage enc tile -> LDS bf16 (R1-style 4-deep pipelined loop, cvt_pk)
    {
        const int rsub = tid >> 7;          // 0..1
        const int c4 = (tid & 127) * 4;     // float index 0..508
#pragma unroll 4
        for (int p = 0; p < 16; ++p) {
            const int m = p * 2 + rsub;
            const float4 vld = *reinterpret_cast<const float4*>(
                &enc[(size_t)((t0 + m) * BB + b) * HH + c4]);
            uint2 pk;
            pk.x = cvt2(vld.x, vld.y);
            pk.y = cvt2(vld.z, vld.w);
            const int idx = (m * 512 + c4) ^ ((m & 7) << 3);
            *reinterpret_cast<uint2*>(&At[idx]) = pk;
        }
    }
    __syncthreads();

    const int wave = tid >> 6;
    const int lane = tid & 63;
    const int lrow = lane & 15;           // A row / B col / D col
    const int lk = (lane >> 4) * 8;       // k sub-offset

    float score_acc[2][4];                 // [m_tile][reg] ; row = mt*16 + (lane>>4)*4 + r
#pragma unroll
    for (int i = 0; i < 2; ++i)
#pragma unroll
        for (int j = 0; j < 4; ++j) score_acc[i][j] = 0.0f;

    for (int chunk = 0; chunk < 4; ++chunk) {
        const int nb = chunk * 128 + wave * 32;
        const int obbase = chunk * 8 + wave * 2;           // ob for ns=0
        const short* Wp = W2p + (size_t)obbase * 16 * 64 * 8;  // slot=(ns*16+ks)*64+lane

        f32x4 acc[2][2];
#pragma unroll
        for (int mt = 0; mt < 2; ++mt)
#pragma unroll
            for (int ns = 0; ns < 2; ++ns) acc[mt][ns] = (f32x4){0.f, 0.f, 0.f, 0.f};

#pragma unroll
        for (int ks = 0; ks < 16; ++ks) {
            const int kc = ks * 32 + lk;
            bf16x8 a[2], bfr[2];
#pragma unroll
            for (int ns = 0; ns < 2; ++ns)
                bfr[ns] = *reinterpret_cast<const bf16x8*>(
                    Wp + ((size_t)(ns * 16 + ks) * 64 + lane) * 8);
#pragma unroll
            for (int mt = 0; mt < 2; ++mt) {
                const int m = mt * 16 + lrow;
                const int idx = (m * 512 + kc) ^ ((m & 7) << 3);
                a[mt] = *reinterpret_cast<const bf16x8*>(&At[idx]);
            }
#pragma unroll
            for (int mt = 0; mt < 2; ++mt)
#pragma unroll
                for (int ns = 0; ns < 2; ++ns)
                    acc[mt][ns] = __builtin_amdgcn_mfma_f32_16x16x32_bf16(
                        a[mt], bfr[ns], acc[mt][ns], 0, 0, 0);
        }

        // epilogue for this o-chunk: tanh + v-weighted accumulate into row partials
#pragma unroll
        for (int ns = 0; ns < 2; ++ns) {
            const int o = nb + ns * 16 + lrow;
            const float hbv = hb[b * 512 + o];
            const float vv = v[o];
#pragma unroll
            for (int mt = 0; mt < 2; ++mt)
#pragma unroll
                for (int r = 0; r < 4; ++r) {
                    const float x = acc[mt][ns][r] + hbv;
                    score_acc[mt][r] = fmaf(fast_tanh(x), vv, score_acc[mt][r]);
                }
        }
    }

    // reduce across the 16 columns held by lanes (low 4 lane bits)
#pragma unroll
    for (int off = 1; off < 16; off <<= 1)
#pragma unroll
        for (int mt = 0; mt < 2; ++mt)
#pragma unroll
            for (int r = 0; r < 4; ++r)
                score_acc[mt][r] += __shfl_xor(score_acc[mt][r], off, 64);

    if (lrow == 0) {
        const int rbase = (lane >> 4) * 4;
#pragma unroll
        for (int mt = 0; mt < 2; ++mt)
#pragma unroll
            for (int r = 0; r < 4; ++r)
                s_red[wave][mt * 16 + rbase + r] = score_acc[mt][r];
    }
    __syncthreads();

    if (tid < 32)
        scores[(size_t)b * TT + t0 + tid] =
            s_red[0][tid] + s_red[1][tid] + s_red[2][tid] + s_red[3][tid];
}

// ---- Kernel 4: softmax over T per b
__global__ void softmax_kernel(const float* __restrict__ scores, float* __restrict__ out) {
    __shared__ float wred[4];
    __shared__ float wsum[4];
    const int b = blockIdx.x;
    const int tid = threadIdx.x;   // 256
    float vals[8];
    float mx = -1e30f;
#pragma unroll
    for (int i = 0; i < 8; ++i) {
        vals[i] = scores[b * TT + i * 256 + tid];
        mx = fmaxf(mx, vals[i]);
    }
#pragma unroll
    for (int off = 32; off; off >>= 1) mx = fmaxf(mx, __shfl_xor(mx, off, 64));
    if ((tid & 63) == 0) wred[tid >> 6] = mx;
    __syncthreads();
    mx = fmaxf(fmaxf(wred[0], wred[1]), fmaxf(wred[2], wred[3]));
    float s = 0.0f;
#pragma unroll
    for (int i = 0; i < 8; ++i) {
        vals[i] = __expf(vals[i] - mx);
        s += vals[i];
    }
#pragma unroll
    for (int off = 32; off; off >>= 1) s += __shfl_xor(s, off, 64);
    if ((tid & 63) == 0) wsum[tid >> 6] = s;
    __syncthreads();
    s = wsum[0] + wsum[1] + wsum[2] + wsum[3];
    const float inv = 1.0f / s;
#pragma unroll
    for (int i = 0; i < 8; ++i) out[b * TT + i * 256 + tid] = vals[i] * inv;
}

extern "C" void kernel_launch(void* const* d_in, const int* in_sizes, int n_in,
                              void* d_out, int out_size, void* d_ws, size_t ws_size,
                              hipStream_t stream) {
    const float* hidden = (const float*)d_in[0];   // (1,B,H)
    const float* enc    = (const float*)d_in[1];   // (T,B,H)
    const float* W      = (const float*)d_in[2];   // (H,2H)
    const float* b_attn = (const float*)d_in[3];   // (H,)
    const float* v      = (const float*)d_in[4];   // (H,)
    float* out = (float*)d_out;                    // (B,1,T)

    char* base = (char*)d_ws;
    short* W2p   = (short*)base;                       // 512*512*2 = 524288 B
    float* hb    = (float*)(base + 524288);            // 32*512*4  =  65536 B
    float* scores= (float*)(base + 524288 + 65536);    // 32*2048*4 = 262144 B

    pack_w2_kernel<<<128, 256, 0, stream>>>(W, W2p);
    hb_kernel<<<64, 256, 0, stream>>>(hidden, W, b_attn, hb);
    attn_main_kernel<<<2048, 256, 0, stream>>>(enc, W2p, hb, v, scores);
    softmax_kernel<<<32, 256, 0, stream>>>(scores, out);
}

// Round 4
// 114.199 us; speedup vs baseline: 1.4933x; 1.4933x over previous
//
#include <hip/hip_runtime.h>
#include <hip/hip_bf16.h>

// Problem: T=2048, B=32, H=512
//   scores[b,t] = sum_o v[o] * tanh( hb[b,o] + sum_h enc[t,b,h] * W2[o,h] )
//   out[b,0,t]  = softmax_t(scores[b,:])
// where hb[b,o] = sum_h hidden[b,h]*W_attn[o,h] + b_attn[o],  W2[o,h] = W_attn[o, 512+h]
//
// R3 lesson: fragment-major W2 repack caused FETCH 70->292MB, WRITE 0.25->121MB and
// slowed everything down; occupancy (21->42%) changed nothing. This round: exact
// round-0 memory structure (row-major W2b, 64-row tiles, 1024 blocks, lb(256,2)),
// pure-VALU changes only (rcp-tanh, cvt_pk staging, s_red reduce).

#define TT 2048
#define BB 32
#define HH 512

typedef __attribute__((ext_vector_type(8))) short bf16x8;
typedef __attribute__((ext_vector_type(4))) float f32x4;

static __device__ __forceinline__ unsigned cvt2(float a, float b) {
    union { __hip_bfloat162 h; unsigned u; } cv;
    cv.h = __float22bfloat162_rn(make_float2(a, b));   // v_cvt_pk_bf16_f32
    return cv.u;
}

static __device__ __forceinline__ unsigned short f2bf(float f) {
    unsigned int u = __float_as_uint(f);
    unsigned int r = (u + 0x7FFFu + ((u >> 16) & 1u)) >> 16;  // RNE
    return (unsigned short)r;
}

// tanh(x) = 1 - 2/(1+e^{2x});  e=inf -> rcp(inf)=0 -> +1;  e=0 -> 1-2 = -1. Inf-safe.
static __device__ __forceinline__ float fast_tanh(float x) {
    float e = __expf(2.0f * x);
    return 1.0f - 2.0f * __builtin_amdgcn_rcpf(1.0f + e);
}

// ---- Kernel 1: convert W2 (= W_attn[:, 512:1024]) to bf16, row-major [512][512]
__global__ void conv_w2_kernel(const float* __restrict__ W, short* __restrict__ W2b) {
    int i = blockIdx.x * 256 + threadIdx.x;        // 262144 total
    int o = i >> 9, h = i & 511;
    W2b[i] = (short)f2bf(W[o * 1024 + 512 + h]);
}

// ---- Kernel 2: hb[b][o] = b_attn[o] + sum_h hidden[b,h] * W_attn[o,h]
__global__ void hb_kernel(const float* __restrict__ hidden, const float* __restrict__ W,
                          const float* __restrict__ b_attn, float* __restrict__ hb) {
    __shared__ float hrow[512];
    int b = blockIdx.x >> 1;
    int o = ((blockIdx.x & 1) << 8) + threadIdx.x;
    for (int h = threadIdx.x; h < 512; h += 256) hrow[h] = hidden[b * 512 + h];
    __syncthreads();
    const float4* wr = reinterpret_cast<const float4*>(W + (size_t)o * 1024);
    const float4* hr = reinterpret_cast<const float4*>(hrow);
    float acc = b_attn[o];
#pragma unroll 8
    for (int i = 0; i < 128; ++i) {
        float4 w = wr[i], h4 = hr[i];
        acc += w.x * h4.x + w.y * h4.y + w.z * h4.z + w.w * h4.w;
    }
    hb[b * 512 + o] = acc;
}

// ---- Kernel 3: fused GEMM + tanh + v-dot -> scores[b][t]
// Block: 256 threads (4 waves). Tile: 64 t-rows for one b, full K=512 in LDS (bf16, swizzled).
// o processed in 4 chunks of 128 (wave w owns cols [chunk*128 + w*32, +32)).
__global__ __launch_bounds__(256, 2) void attn_main_kernel(
    const float* __restrict__ enc, const short* __restrict__ W2b,
    const float* __restrict__ hb, const float* __restrict__ v,
    float* __restrict__ scores)
{
    __shared__ short At[64 * 512];   // 64KB, swizzled: idx = (m*512+c) ^ ((m&7)<<3)
    __shared__ float s_red[4][64];

    const int tid = threadIdx.x;
    const int b = blockIdx.x >> 5;          // 32 b's
    const int t0 = (blockIdx.x & 31) * 64;  // 32 t-blocks

    // ---- stage enc tile -> LDS bf16 (coalesced fp32 reads, cvt_pk conversion)
    {
        const int rsub = tid >> 7;          // 0..1
        const int c4 = (tid & 127) * 4;     // 0..508
#pragma unroll 4
        for (int p = 0; p < 32; ++p) {
            const int m = p * 2 + rsub;
            const float4 vld = *reinterpret_cast<const float4*>(
                &enc[(size_t)((t0 + m) * BB + b) * HH + c4]);
            uint2 pk;
            pk.x = cvt2(vld.x, vld.y);
            pk.y = cvt2(vld.z, vld.w);
            const int idx = (m * 512 + c4) ^ ((m & 7) << 3);
            *reinterpret_cast<uint2*>(&At[idx]) = pk;
        }
    }
    __syncthreads();

    const int wave = tid >> 6;
    const int lane = tid & 63;
    const int lrow = lane & 15;           // A row / B col / D col
    const int lk = (lane >> 4) * 8;       // k sub-offset

    float score_acc[4][4];                 // [m_tile][reg] ; row = mt*16 + (lane>>4)*4 + r
#pragma unroll
    for (int i = 0; i < 4; ++i)
#pragma unroll
        for (int j = 0; j < 4; ++j) score_acc[i][j] = 0.0f;

#pragma unroll
    for (int chunk = 0; chunk < 4; ++chunk) {
        const int nb = chunk * 128 + wave * 32;
        f32x4 acc[4][2];
#pragma unroll
        for (int mt = 0; mt < 4; ++mt)
#pragma unroll
            for (int ns = 0; ns < 2; ++ns) acc[mt][ns] = (f32x4){0.f, 0.f, 0.f, 0.f};

#pragma unroll 2
        for (int ks = 0; ks < 16; ++ks) {
            const int kc = ks * 32 + lk;
            bf16x8 a[4], bf[2];
#pragma unroll
            for (int mt = 0; mt < 4; ++mt) {
                const int m = mt * 16 + lrow;
                const int idx = (m * 512 + kc) ^ ((m & 7) << 3);
                a[mt] = *reinterpret_cast<const bf16x8*>(&At[idx]);
            }
#pragma unroll
            for (int ns = 0; ns < 2; ++ns) {
                const int o = nb + ns * 16 + lrow;
                bf[ns] = *reinterpret_cast<const bf16x8*>(&W2b[o * 512 + kc]);
            }
#pragma unroll
            for (int mt = 0; mt < 4; ++mt)
#pragma unroll
                for (int ns = 0; ns < 2; ++ns)
                    acc[mt][ns] = __builtin_amdgcn_mfma_f32_16x16x32_bf16(
                        a[mt], bf[ns], acc[mt][ns], 0, 0, 0);
        }

        // epilogue for this o-chunk: tanh + v-weighted accumulate into row partials
#pragma unroll
        for (int ns = 0; ns < 2; ++ns) {
            const int o = nb + ns * 16 + lrow;
            const float hbv = hb[b * 512 + o];
            const float vv = v[o];
#pragma unroll
            for (int mt = 0; mt < 4; ++mt)
#pragma unroll
                for (int r = 0; r < 4; ++r) {
                    const float x = acc[mt][ns][r] + hbv;
                    score_acc[mt][r] = fmaf(fast_tanh(x), vv, score_acc[mt][r]);
                }
        }
    }

    // reduce across the 16 columns held by lanes (low 4 lane bits)
#pragma unroll
    for (int off = 1; off < 16; off <<= 1)
#pragma unroll
        for (int mt = 0; mt < 4; ++mt)
#pragma unroll
            for (int r = 0; r < 4; ++r)
                score_acc[mt][r] += __shfl_xor(score_acc[mt][r], off, 64);

    if (lrow == 0) {
        const int rbase = (lane >> 4) * 4;
#pragma unroll
        for (int mt = 0; mt < 4; ++mt)
#pragma unroll
            for (int r = 0; r < 4; ++r)
                s_red[wave][mt * 16 + rbase + r] = score_acc[mt][r];
    }
    __syncthreads();

    if (tid < 64)
        scores[(size_t)b * TT + t0 + tid] =
            s_red[0][tid] + s_red[1][tid] + s_red[2][tid] + s_red[3][tid];
}

// ---- Kernel 4: softmax over T per b
__global__ void softmax_kernel(const float* __restrict__ scores, float* __restrict__ out) {
    __shared__ float wred[4];
    __shared__ float wsum[4];
    const int b = blockIdx.x;
    const int tid = threadIdx.x;   // 256
    float vals[8];
    float mx = -1e30f;
#pragma unroll
    for (int i = 0; i < 8; ++i) {
        vals[i] = scores[b * TT + i * 256 + tid];
        mx = fmaxf(mx, vals[i]);
    }
#pragma unroll
    for (int off = 32; off; off >>= 1) mx = fmaxf(mx, __shfl_xor(mx, off, 64));
    if ((tid & 63) == 0) wred[tid >> 6] = mx;
    __syncthreads();
    mx = fmaxf(fmaxf(wred[0], wred[1]), fmaxf(wred[2], wred[3]));
    float s = 0.0f;
#pragma unroll
    for (int i = 0; i < 8; ++i) {
        vals[i] = __expf(vals[i] - mx);
        s += vals[i];
    }
#pragma unroll
    for (int off = 32; off; off >>= 1) s += __shfl_xor(s, off, 64);
    if ((tid & 63) == 0) wsum[tid >> 6] = s;
    __syncthreads();
    s = wsum[0] + wsum[1] + wsum[2] + wsum[3];
    const float inv = 1.0f / s;
#pragma unroll
    for (int i = 0; i < 8; ++i) out[b * TT + i * 256 + tid] = vals[i] * inv;
}

extern "C" void kernel_launch(void* const* d_in, const int* in_sizes, int n_in,
                              void* d_out, int out_size, void* d_ws, size_t ws_size,
                              hipStream_t stream) {
    const float* hidden = (const float*)d_in[0];   // (1,B,H)
    const float* enc    = (const float*)d_in[1];   // (T,B,H)
    const float* W      = (const float*)d_in[2];   // (H,2H)
    const float* b_attn = (const float*)d_in[3];   // (H,)
    const float* v      = (const float*)d_in[4];   // (H,)
    float* out = (float*)d_out;                    // (B,1,T)

    char* base = (char*)d_ws;
    short* W2b   = (short*)base;                       // 512*512*2 = 524288 B
    float* hb    = (float*)(base + 524288);            // 32*512*4  =  65536 B
    float* scores= (float*)(base + 524288 + 65536);    // 32*2048*4 = 262144 B

    conv_w2_kernel<<<1024, 256, 0, stream>>>(W, W2b);
    hb_kernel<<<64, 256, 0, stream>>>(hidden, W, b_attn, hb);
    attn_main_kernel<<<1024, 256, 0, stream>>>(enc, W2b, hb, v, scores);
    softmax_kernel<<<32, 256, 0, stream>>>(scores, out);
}